// Round 5
// baseline (268.558 us; speedup 1.0000x reference)
//
#include <hip/hip_runtime.h>
#include <hip/hip_bf16.h>
#include <stdint.h>

// Problem constants
#define Bsz 4
#define Tsz 2048
#define Csz 1024
#define Hn  16
#define Dh  64
#define BH  (Bsz*Hn)      // 64
#define Mrows (Bsz*Tsz)   // 8192
#define N1  (3*Csz)       // 3072

typedef short s16x8 __attribute__((ext_vector_type(8)));
typedef short s16x4 __attribute__((ext_vector_type(4)));
typedef float fx4   __attribute__((ext_vector_type(4)));

static __device__ __forceinline__ short f2bf(float x) {
  __hip_bfloat16 h = __float2bfloat16(x);   // RNE
  return __builtin_bit_cast(short, h);
}

#define GLDS16(g, l) __builtin_amdgcn_global_load_lds( \
    (const __attribute__((address_space(1))) void*)(g), \
    (__attribute__((address_space(3))) void*)(l), 16, 0, 0)

// ---------------- f32 -> bf16 bulk convert ----------------
__global__ void cvt_kernel(const float* __restrict__ in, short* __restrict__ out, int n4) {
  int i = blockIdx.x * blockDim.x + threadIdx.x;
  int stride = blockDim.x * gridDim.x;
  for (; i < n4; i += stride) {
    float4 v = ((const float4*)in)[i];
    s16x4 o;
    o.x = f2bf(v.x); o.y = f2bf(v.y); o.z = f2bf(v.z); o.w = f2bf(v.w);
    ((s16x4*)out)[i] = o;
  }
}

// ------------- (K,N) f32 -> (N,K) bf16 transpose ----------
__global__ void transpose_cvt_kernel(const float* __restrict__ w, short* __restrict__ wt,
                                     int K, int N) {
  __shared__ float tile[32][33];
  int tc = threadIdx.x & 31;
  int tr = threadIdx.x >> 5;      // 0..7
  int n0 = blockIdx.x * 32;
  int k0 = blockIdx.y * 32;
#pragma unroll
  for (int p = 0; p < 4; p++) {
    int r = tr + p*8;
    tile[r][tc] = w[(size_t)(k0 + r) * N + (n0 + tc)];
  }
  __syncthreads();
#pragma unroll
  for (int p = 0; p < 4; p++) {
    int r = tr + p*8;   // output (n) row
    wt[(size_t)(n0 + r) * K + (k0 + tc)] = f2bf(tile[tc][r]);
  }
}

static __device__ __forceinline__ s16x8 lds_frag(const short* p, int off) {
  return *(const s16x8*)(p + off);
}

#define WAITV(n) __asm__ __volatile__("s_waitcnt vmcnt(" #n ")" ::: "memory")

// ============ GEMM variant A: 256x256 tile (R9 verbatim; QKV, 81 µs) ======
// R10 post-mortem: 384-wide tiles hit the 256-reg/lane cliff (acc 192 AGPR)
// and split heads across blocks (WRITE amplification 49->73 MB). 256x256
// with acc 8x4 fits and writes full cachelines. Keep it.
#define TILE_SH 8192   // 256 rows * 32 shorts per buffer

__global__ __launch_bounds__(512) void gemm_bt256_kernel(
    const short* __restrict__ A, const short* __restrict__ Bt,
    float* __restrict__ Cf,
    short* __restrict__ Qo, short* __restrict__ Ko, short* __restrict__ Vo,
    int Mdim, int Ndim, int Kdim, int mode)
{
  __shared__ __align__(16) short sA4[4*TILE_SH];   // 64 KB
  __shared__ __align__(16) short sB4[4*TILE_SH];   // 64 KB
  const int tid  = threadIdx.x;
  const int lane = tid & 63;
  const int lr   = lane & 15;
  const int lq   = lane >> 4;
  const int wv   = tid >> 6;               // 0..7
  const int wm   = wv >> 2;                // 0..1 (m half)
  const int wn   = wv & 3;                 // 0..3 (n quarter)
  const int nb   = Ndim >> 8;              // 256-wide n tiles
  const int nwg  = (int)gridDim.x;
  const int orig = (int)blockIdx.x;
  const int wgid = (orig & 7) * (nwg >> 3) + (orig >> 3);
  const int bm   = wgid / nb;
  const int bn   = wgid % nb;

  const short* Ab = A  + (size_t)bm * 256 * Kdim;
  const short* Bb = Bt + (size_t)bn * 256 * Kdim;

  const int rr0 = tid >> 2,        ss0 = ((tid & 3) ^ ((rr0 >> 1) & 3)) * 8;
  const int rr1 = rr0 + 128,       ss1 = ((tid & 3) ^ ((rr1 >> 1) & 3)) * 8;
  const short* gA0 = Ab + (size_t)rr0 * Kdim + ss0;
  const short* gA1 = Ab + (size_t)rr1 * Kdim + ss1;
  const short* gB0 = Bb + (size_t)rr0 * Kdim + ss0;
  const short* gB1 = Bb + (size_t)rr1 * Kdim + ss1;

  int offA[8], offB[4];
#pragma unroll
  for (int mt = 0; mt < 8; mt++) {
    int row = wm*128 + mt*16 + lr;
    offA[mt] = row*32 + ((lq ^ ((row >> 1) & 3)) << 3);
  }
#pragma unroll
  for (int nt = 0; nt < 4; nt++) {
    int row = wn*64 + nt*16 + lr;
    offB[nt] = row*32 + ((lq ^ ((row >> 1) & 3)) << 3);
  }

  fx4 acc[8][4];
#pragma unroll
  for (int i = 0; i < 8; i++)
#pragma unroll
    for (int j = 0; j < 4; j++) acc[i][j] = (fx4){0.f, 0.f, 0.f, 0.f};

  const int NIT = Kdim >> 5;   // K-tiles of 32 (32 for K=1024)

  // prologue: stage tiles 0,1,2
#pragma unroll
  for (int k = 0; k < 3; k++) {
    short* dA = sA4 + k*TILE_SH;
    short* dB = sB4 + k*TILE_SH;
    GLDS16(gA0 + k*32, dA + tid*8);
    GLDS16(gA1 + k*32, dA + (tid+512)*8);
    GLDS16(gB0 + k*32, dB + tid*8);
    GLDS16(gB1 + k*32, dB + (tid+512)*8);
  }
  WAITV(8);   // tile 0 resident
  __builtin_amdgcn_s_barrier();
  __builtin_amdgcn_sched_barrier(0);

  for (int t = 0; t < NIT; ++t) {
    const short* cA = sA4 + (t & 3)*TILE_SH;
    const short* cB = sB4 + (t & 3)*TILE_SH;
    short* eA = sA4 + ((t + 3) & 3)*TILE_SH;
    short* eB = sB4 + ((t + 3) & 3)*TILE_SH;
    const bool pre = (t + 3 < NIT);

    // ---- phase 0: mt 0..3 x nt 0..3 ----
    s16x8 bfr[4], afr[4];
#pragma unroll
    for (int nt = 0; nt < 4; nt++) bfr[nt] = lds_frag(cB, offB[nt]);
#pragma unroll
    for (int mt = 0; mt < 4; mt++) afr[mt] = lds_frag(cA, offA[mt]);
    if (pre) {
      GLDS16(gA0 + (t+3)*32, eA + tid*8);
      GLDS16(gA1 + (t+3)*32, eA + (tid+512)*8);
    }
    __builtin_amdgcn_s_barrier();
    __asm__ __volatile__("s_waitcnt lgkmcnt(0)" ::: "memory");
    __builtin_amdgcn_sched_barrier(0);
    __builtin_amdgcn_s_setprio(1);
#pragma unroll
    for (int mt = 0; mt < 4; mt++)
#pragma unroll
      for (int nt = 0; nt < 4; nt++)
        acc[mt][nt] = __builtin_amdgcn_mfma_f32_16x16x32_bf16(afr[mt], bfr[nt], acc[mt][nt], 0, 0, 0);
    __builtin_amdgcn_s_setprio(0);
    __builtin_amdgcn_sched_barrier(0);
    __builtin_amdgcn_s_barrier();
    __builtin_amdgcn_sched_barrier(0);

    // ---- phase 1: mt 4..7 x nt 0..3 (B-frags held in regs) ----
#pragma unroll
    for (int mt = 0; mt < 4; mt++) afr[mt] = lds_frag(cA, offA[mt+4]);
    if (pre) {
      GLDS16(gB0 + (t+3)*32, eB + tid*8);
      GLDS16(gB1 + (t+3)*32, eB + (tid+512)*8);
    }
    __builtin_amdgcn_s_barrier();
    __asm__ __volatile__("s_waitcnt lgkmcnt(0)" ::: "memory");
    __builtin_amdgcn_sched_barrier(0);
    __builtin_amdgcn_s_setprio(1);
#pragma unroll
    for (int mt = 0; mt < 4; mt++)
#pragma unroll
      for (int nt = 0; nt < 4; nt++)
        acc[mt+4][nt] = __builtin_amdgcn_mfma_f32_16x16x32_bf16(afr[mt], bfr[nt], acc[mt+4][nt], 0, 0, 0);
    __builtin_amdgcn_s_setprio(0);
    __builtin_amdgcn_sched_barrier(0);
    if (t + 3 < NIT)      { WAITV(8); }
    else if (t + 2 < NIT) { WAITV(4); }
    else if (t + 1 < NIT) { WAITV(0); }
    __builtin_amdgcn_s_barrier();
    __builtin_amdgcn_sched_barrier(0);
  }

  const int gm0 = bm*256 + wm*128;
  const int gn0 = bn*256 + wn*64;
  if (mode == 0) {
#pragma unroll
    for (int mt = 0; mt < 8; mt++)
#pragma unroll
      for (int nt = 0; nt < 4; nt++) {
        int col = gn0 + nt*16 + lr;
#pragma unroll
        for (int r = 0; r < 4; r++) {
          int row = gm0 + mt*16 + lq*4 + r;
          Cf[(size_t)row * Ndim + col] = acc[mt][nt][r];
        }
      }
  } else {
#pragma unroll
    for (int mt = 0; mt < 8; mt++)
#pragma unroll
      for (int nt = 0; nt < 4; nt++) {
        int n   = gn0 + nt*16 + lr;
        int sec = n >> 10;        // 0=q 1=k 2=v (uniform per nt)
        int cc  = n & 1023;
        int hh  = cc >> 6;
        int dd  = cc & 63;
        if (sec == 2) {
          int tt0 = gm0 + mt*16 + lq*4;
          int bb  = tt0 >> 11;
          int bh  = bb * Hn + hh;
          s16x4 pk;
          pk.x = f2bf(acc[mt][nt][0]); pk.y = f2bf(acc[mt][nt][1]);
          pk.z = f2bf(acc[mt][nt][2]); pk.w = f2bf(acc[mt][nt][3]);
          *(s16x4*)(Vo + ((size_t)bh * Dh + dd) * Tsz + (tt0 & 2047)) = pk;
        } else {
#pragma unroll
          for (int r = 0; r < 4; r++) {
            int m  = gm0 + mt*16 + lq*4 + r;
            int bb = m >> 11;
            int tt = m & 2047;
            int bh = bb * Hn + hh;
            short v = f2bf(acc[mt][nt][r]);
            if (sec == 0) Qo[((size_t)bh * Tsz + tt) * Dh + dd] = v;
            else          Ko[((size_t)bh * Tsz + tt) * Dh + dd] = v;
          }
        }
      }
  }
}

// ============ GEMM variant B: 128x256 tile, BK=64 (R8 verbatim; proj) =====
// Grid for proj = 64x4 = 256 blocks = exactly one CU round; best measured
// proj configuration (R8 total 254.8 was the session best).
__global__ __launch_bounds__(512) void gemm_bt128_kernel(
    const short* __restrict__ A, const short* __restrict__ Bt,
    float* __restrict__ Cf,
    short* __restrict__ Qo, short* __restrict__ Ko, short* __restrict__ Vo,
    int Mdim, int Ndim, int Kdim, int mode)
{
  __shared__ __align__(16) short sA[3][128*64];   // 3 x 16 KB
  __shared__ __align__(16) short sB[3][256*64];   // 3 x 32 KB
  const int tid  = threadIdx.x;
  const int lane = tid & 63;
  const int lr   = lane & 15;
  const int lq   = lane >> 4;
  const int wv   = tid >> 6;               // 0..7
  const int nb   = Ndim >> 8;              // 256-wide n tiles
  const int nwg  = (int)gridDim.x;
  const int orig = (int)blockIdx.x;
  const int wgid = (orig & 7) * (nwg >> 3) + (orig >> 3);
  const int bm   = wgid / nb;
  const int bn   = wgid % nb;
  const int m_off = (wv & 1) << 6;         // 0 / 64
  const int n_off = (wv >> 1) << 6;        // 0 / 64 / 128 / 192

  const short* Ab = A  + (size_t)bm * 128 * Kdim;
  const short* Bb = Bt + (size_t)bn * 256 * Kdim;

  const short* gA[2];
  const short* gB[4];
#pragma unroll
  for (int j = 0; j < 2; j++) {
    int c = tid + 512*j, r = c >> 3, o = ((c & 7) ^ (r & 7)) * 8;
    gA[j] = Ab + (size_t)r * Kdim + o;
  }
#pragma unroll
  for (int j = 0; j < 4; j++) {
    int c = tid + 512*j, r = c >> 3, o = ((c & 7) ^ (r & 7)) * 8;
    gB[j] = Bb + (size_t)r * Kdim + o;
  }

  int offA[4][2], offB[4][2];
#pragma unroll
  for (int ft = 0; ft < 4; ft++)
#pragma unroll
    for (int kk = 0; kk < 2; kk++) {
      int ra = m_off + ft*16 + lr;
      offA[ft][kk] = ra*64 + ((((kk<<2) | lq) ^ (ra & 7)) << 3);
      int rb = n_off + ft*16 + lr;
      offB[ft][kk] = rb*64 + ((((kk<<2) | lq) ^ (rb & 7)) << 3);
    }

  fx4 acc[4][4];
#pragma unroll
  for (int i = 0; i < 4; i++)
#pragma unroll
    for (int j = 0; j < 4; j++) acc[i][j] = (fx4){0.f, 0.f, 0.f, 0.f};

  auto STAGE_P1 = [&](int k0, short* dA, short* dB) {   // 3 loads
    GLDS16(gA[0] + k0, dA + tid*8);
    GLDS16(gA[1] + k0, dA + (tid+512)*8);
    GLDS16(gB[0] + k0, dB + tid*8);
  };
  auto STAGE_P2 = [&](int k0, short* dB) {              // 3 loads
    GLDS16(gB[1] + k0, dB + (tid+512)*8);
    GLDS16(gB[2] + k0, dB + (tid+1024)*8);
    GLDS16(gB[3] + k0, dB + (tid+1536)*8);
  };

  const int NIT = Kdim >> 6;   // K-tiles of 64 (16 for K=1024)

  STAGE_P1(0,  sA[0], sB[0]); STAGE_P2(0,  sB[0]);
  STAGE_P1(64, sA[1], sB[1]); STAGE_P2(64, sB[1]);
  WAITV(6);
  __builtin_amdgcn_s_barrier();

  const short *cA = sA[0], *cB = sB[0];
  const short *nA = sA[1], *nB = sB[1];
  short *eA = sA[2], *eB = sB[2];

  for (int t = 0; t < NIT; ++t) {
    if (t + 2 < NIT) STAGE_P1((t+2)*64, eA, eB);

    // ---- phase 1: n-frags 0,1 ----
    s16x8 af[4][2], bf[2][2];
#pragma unroll
    for (int mt = 0; mt < 4; mt++)
#pragma unroll
      for (int kk = 0; kk < 2; kk++)
        af[mt][kk] = lds_frag(cA, offA[mt][kk]);
#pragma unroll
    for (int nt = 0; nt < 2; nt++)
#pragma unroll
      for (int kk = 0; kk < 2; kk++)
        bf[nt][kk] = lds_frag(cB, offB[nt][kk]);
    __builtin_amdgcn_s_setprio(1);
#pragma unroll
    for (int kk = 0; kk < 2; kk++)
#pragma unroll
      for (int mt = 0; mt < 4; mt++) {
        acc[mt][0] = __builtin_amdgcn_mfma_f32_16x16x32_bf16(af[mt][kk], bf[0][kk], acc[mt][0], 0, 0, 0);
        acc[mt][1] = __builtin_amdgcn_mfma_f32_16x16x32_bf16(af[mt][kk], bf[1][kk], acc[mt][1], 0, 0, 0);
      }
    __builtin_amdgcn_s_setprio(0);
    __builtin_amdgcn_sched_barrier(0);
    __builtin_amdgcn_s_barrier();

    // ---- phase 2: n-frags 2,3 ----
    if (t + 2 < NIT) STAGE_P2((t+2)*64, eB);
#pragma unroll
    for (int nt = 0; nt < 2; nt++)
#pragma unroll
      for (int kk = 0; kk < 2; kk++)
        bf[nt][kk] = lds_frag(cB, offB[nt+2][kk]);
    __builtin_amdgcn_s_setprio(1);
#pragma unroll
    for (int kk = 0; kk < 2; kk++)
#pragma unroll
      for (int mt = 0; mt < 4; mt++) {
        acc[mt][2] = __builtin_amdgcn_mfma_f32_16x16x32_bf16(af[mt][kk], bf[0][kk], acc[mt][2], 0, 0, 0);
        acc[mt][3] = __builtin_amdgcn_mfma_f32_16x16x32_bf16(af[mt][kk], bf[1][kk], acc[mt][3], 0, 0, 0);
      }
    __builtin_amdgcn_s_setprio(0);
    __builtin_amdgcn_sched_barrier(0);
    if (t + 2 < NIT)      { WAITV(6); }
    else if (t + 1 < NIT) { WAITV(0); }
    __builtin_amdgcn_s_barrier();

    const short *tAp = cA, *tBp = cB;
    cA = nA; cB = nB;
    nA = eA; nB = eB;
    eA = (short*)tAp; eB = (short*)tBp;
  }

  const int gm0 = bm*128 + m_off;
  const int gn0 = bn*256 + n_off;
  if (mode == 0) {
#pragma unroll
    for (int mt = 0; mt < 4; mt++)
#pragma unroll
      for (int nt = 0; nt < 4; nt++) {
        int col = gn0 + nt*16 + lr;
#pragma unroll
        for (int r = 0; r < 4; r++) {
          int row = gm0 + mt*16 + lq*4 + r;
          Cf[(size_t)row * Ndim + col] = acc[mt][nt][r];
        }
      }
  } else {
#pragma unroll
    for (int mt = 0; mt < 4; mt++)
#pragma unroll
      for (int nt = 0; nt < 4; nt++) {
        int n   = gn0 + nt*16 + lr;
        int sec = n >> 10;
        int cc  = n & 1023;
        int hh  = cc >> 6;
        int dd  = cc & 63;
        if (sec == 2) {
          int tt0 = gm0 + mt*16 + lq*4;
          int bb  = tt0 >> 11;
          int bh  = bb * Hn + hh;
          s16x4 pk;
          pk.x = f2bf(acc[mt][nt][0]); pk.y = f2bf(acc[mt][nt][1]);
          pk.z = f2bf(acc[mt][nt][2]); pk.w = f2bf(acc[mt][nt][3]);
          *(s16x4*)(Vo + ((size_t)bh * Dh + dd) * Tsz + (tt0 & 2047)) = pk;
        } else {
#pragma unroll
          for (int r = 0; r < 4; r++) {
            int m  = gm0 + mt*16 + lq*4 + r;
            int bb = m >> 11;
            int tt = m & 2047;
            int bh = bb * Hn + hh;
            short v = f2bf(acc[mt][nt][r]);
            if (sec == 0) Qo[((size_t)bh * Tsz + tt) * Dh + dd] = v;
            else          Ko[((size_t)bh * Tsz + tt) * Dh + dd] = v;
          }
        }
      }
  }
}

// ---------------- flash-style causal attention ----------------------------
// R11: 8 waves / 512 threads per block, 256 q-rows per block (grid 64x8).
// Halves staged K/V traffic per q-row (278 -> 147 MB total) — the attn-side
// analog of the GEMM's staging-delivery bound. LDS 69 KB -> 2 blocks/CU; all
// 512 blocks co-resident (no round quantization). qb = y<4 ? 7-y : y-4 pairs
// heavy+light blocks on a CU under round-robin dispatch (36 tiles/CU
// uniform). T5 setprio around both MFMA clusters (attn regime, m191).
#define PPITCH 72   // 64 keys + 8 pad; 2-way banks (free)

static __device__ __forceinline__ void attn_stage(
    const short* __restrict__ Kp, const short* __restrict__ Vp, int kbase,
    short* __restrict__ sK, short* __restrict__ sV,
    int c0, int r0, int g0)
{
  GLDS16(Kp + (size_t)(kbase + r0)*Dh + g0, sK + c0*8);
  GLDS16(Vp + (size_t)r0*Tsz + kbase + g0, sV + c0*8);
}

static __device__ __forceinline__ void attn_compute(
    const short* __restrict__ sK, const short* __restrict__ sV,
    int kbase, int q0, int lr, int lq, int sw,
    short* __restrict__ pb, const s16x8 bq[2][2], fx4 o[2][4], float li[2])
{
  const float sc = 0.125f * 1.44269504f;   // 1/sqrt(64) * log2(e)
  const bool masked = (kbase + 63 > q0);   // wave-uniform

  // S^T = K·Q^T for both q-frags, sharing the K A-frag reads
  fx4 s[2][4];
#pragma unroll
  for (int j = 0; j < 2; j++)
#pragma unroll
    for (int mt = 0; mt < 4; mt++) s[j][mt] = (fx4){0.f,0.f,0.f,0.f};
  __builtin_amdgcn_s_setprio(1);
#pragma unroll
  for (int mt = 0; mt < 4; mt++)
#pragma unroll
    for (int kk = 0; kk < 2; kk++) {
      const s16x8 akf = *(const s16x8*)(sK + (mt*16 + lr)*64 + ((kk*4 + lq) ^ sw)*8);
      s[0][mt] = __builtin_amdgcn_mfma_f32_16x16x32_bf16(akf, bq[0][kk], s[0][mt], 0, 0, 0);
      s[1][mt] = __builtin_amdgcn_mfma_f32_16x16x32_bf16(akf, bq[1][kk], s[1][mt], 0, 0, 0);
    }
  __builtin_amdgcn_s_setprio(0);

  // softmax (no running max) + P^T staging, per q-frag
#pragma unroll
  for (int j = 0; j < 2; j++) {
    const int qg = q0 + 16*j + lr;
    float p[16];
#pragma unroll
    for (int mt = 0; mt < 4; mt++)
#pragma unroll
      for (int r = 0; r < 4; r++) {
        float v = s[j][mt][r];
        if (masked) {
          int jg = kbase + mt*16 + lq*4 + r;
          v = (jg <= qg) ? v : -1e30f;
        }
        p[mt*4 + r] = __builtin_amdgcn_exp2f(v * sc);
      }
    float s8[8];
#pragma unroll
    for (int i = 0; i < 8; i++) s8[i] = p[i] + p[i+8];
    float s4[4];
#pragma unroll
    for (int i = 0; i < 4; i++) s4[i] = s8[i] + s8[i+4];
    li[j] += (s4[0] + s4[2]) + (s4[1] + s4[3]);
#pragma unroll
    for (int mt = 0; mt < 4; mt++) {
      s16x4 pk;
      pk.x = f2bf(p[mt*4+0]); pk.y = f2bf(p[mt*4+1]);
      pk.z = f2bf(p[mt*4+2]); pk.w = f2bf(p[mt*4+3]);
      *(s16x4*)(pb + (16*j + lr)*PPITCH + mt*16 + lq*4) = pk;
    }
  }
  __asm__ __volatile__("" ::: "memory");  // pin pbuf write->read (DS in-order/wave)
  s16x8 pf[2][2];
#pragma unroll
  for (int j = 0; j < 2; j++)
#pragma unroll
    for (int kk = 0; kk < 2; kk++)
      pf[j][kk] = *(const s16x8*)(pb + (16*j + lr)*PPITCH + kk*32 + lq*8);
  __asm__ __volatile__("" ::: "memory");  // pin reads before next tile's writes

  // O^T += V^T·P^T, sharing the V A-frag reads across q-frags
  __builtin_amdgcn_s_setprio(1);
#pragma unroll
  for (int dt = 0; dt < 4; dt++)
#pragma unroll
    for (int kk = 0; kk < 2; kk++) {
      const s16x8 avf = *(const s16x8*)(sV + (dt*16 + lr)*64 + ((kk*4 + lq) ^ sw)*8);
      o[0][dt] = __builtin_amdgcn_mfma_f32_16x16x32_bf16(avf, pf[0][kk], o[0][dt], 0, 0, 0);
      o[1][dt] = __builtin_amdgcn_mfma_f32_16x16x32_bf16(avf, pf[1][kk], o[1][dt], 0, 0, 0);
    }
  __builtin_amdgcn_s_setprio(0);
}

__global__ __launch_bounds__(512) void attn_kernel(
    const short* __restrict__ Qb, const short* __restrict__ Kb,
    const short* __restrict__ Vt, short* __restrict__ Y)
{
  __shared__ __align__(16) short sK[2][64*64];     // 16 KB
  __shared__ __align__(16) short sV[2][64*64];     // 16 KB
  __shared__ __align__(16) short pbuf[8][32*PPITCH];  // 36.9 KB
  const int tid  = threadIdx.x;
  const int lane = tid & 63;
  const int wv   = tid >> 6;               // 0..7
  const int lr   = lane & 15;
  const int lq   = lane >> 4;
  const int sw   = lr & 7;
  const int bh   = blockIdx.x;
  const int y    = (int)blockIdx.y;        // 0..7
  const int qb   = (y < 4) ? (7 - y) : (y - 4);  // heavy+light CU pairing
  const int b    = bh >> 4;
  const int h    = bh & 15;
  const int q0   = qb*256 + wv*32;         // wave covers q0..q0+31

  const short* Qp = Qb + (size_t)bh * Tsz * Dh;
  const short* Kp = Kb + (size_t)bh * Tsz * Dh;
  const short* Vp = Vt + (size_t)bh * Dh * Tsz;
  short* pb = pbuf[wv];

  const int c0 = tid, r0 = c0 >> 3, g0 = (((c0 & 7) ^ (r0 & 7)) * 8);

  // Q B-frags for both q-subtiles: B[k=d(lq*8+j)][n=q(lr)]
  s16x8 bq[2][2];
#pragma unroll
  for (int j = 0; j < 2; j++)
#pragma unroll
    for (int kk = 0; kk < 2; kk++)
      bq[j][kk] = *(const s16x8*)(Qp + (size_t)(q0 + 16*j + lr)*Dh + kk*32 + lq*8);

  fx4 o[2][4];
#pragma unroll
  for (int j = 0; j < 2; j++)
#pragma unroll
    for (int i = 0; i < 4; i++) o[j][i] = (fx4){0.f, 0.f, 0.f, 0.f};
  float li[2] = {0.f, 0.f};

  const int ntiles = 4*qb + 4;             // even; keys 0 .. qb*256+255
  attn_stage(Kp, Vp, 0, sK[0], sV[0], c0, r0, g0);
  for (int kt = 0; kt < ntiles; kt += 2) {
    __syncthreads();
    if (kt + 1 < ntiles) attn_stage(Kp, Vp, (kt+1)*64, sK[1], sV[1], c0, r0, g0);
    if (kt*64 <= q0 + 31)
      attn_compute(sK[0], sV[0], kt*64, q0, lr, lq, sw, pb, bq, o, li);
    __syncthreads();
    if (kt + 2 < ntiles) attn_stage(Kp, Vp, (kt+2)*64, sK[0], sV[0], c0, r0, g0);
    if ((kt+1)*64 <= q0 + 31)
      attn_compute(sK[1], sV[1], (kt+1)*64, q0, lr, lq, sw, pb, bq, o, li);
  }

  // combine the 4 lq-replica partial sums; write O^T (lane q fixed per frag)
#pragma unroll
  for (int j = 0; j < 2; j++) {
    float l = li[j];
    l += __shfl_xor(l, 16);
    l += __shfl_xor(l, 32);
    float inv = 1.0f / l;
#pragma unroll
    for (int dt = 0; dt < 4; dt++) {
      s16x4 yk;
      yk.x = f2bf(o[j][dt][0]*inv); yk.y = f2bf(o[j][dt][1]*inv);
      yk.z = f2bf(o[j][dt][2]*inv); yk.w = f2bf(o[j][dt][3]*inv);
      *(s16x4*)(Y + ((size_t)b*Tsz + q0 + 16*j + lr)*Csz + h*Dh + dt*16 + lq*4) = yk;
    }
  }
}

// ---------------- launcher ----------------
extern "C" void kernel_launch(void* const* d_in, const int* in_sizes, int n_in,
                              void* d_out, int out_size, void* d_ws, size_t ws_size,
                              hipStream_t stream)
{
  const float* x  = (const float*)d_in[0];
  const float* wq = (const float*)d_in[1];   // (C, 3C)
  const float* wp = (const float*)d_in[2];   // (C, C)
  float* out = (float*)d_out;

  char* ws = (char*)d_ws;
  size_t off = 0;
  short* xb  = (short*)(ws + off); off += (size_t)Mrows*Csz*2;
  short* wqT = (short*)(ws + off); off += (size_t)N1*Csz*2;
  short* wpT = (short*)(ws + off); off += (size_t)Csz*Csz*2;
  short* Qb  = (short*)(ws + off); off += (size_t)BH*Tsz*Dh*2;
  short* Kb  = (short*)(ws + off); off += (size_t)BH*Tsz*Dh*2;
  short* Vt  = (short*)(ws + off); off += (size_t)BH*Dh*Tsz*2;
  short* Yb  = (short*)(ws + off); off += (size_t)Mrows*Csz*2;

  cvt_kernel<<<1024, 256, 0, stream>>>(x, xb, Mrows*Csz/4);
  transpose_cvt_kernel<<<dim3(N1/32, Csz/32), 256, 0, stream>>>(wq, wqT, Csz, N1);
  transpose_cvt_kernel<<<dim3(Csz/32, Csz/32), 256, 0, stream>>>(wp, wpT, Csz, Csz);
  gemm_bt256_kernel<<<(Mrows/256)*(N1/256), 512, 0, stream>>>(
      xb, wqT, nullptr, Qb, Kb, Vt, Mrows, N1, Csz, 1);
  attn_kernel<<<dim3(BH, Tsz/256), 512, 0, stream>>>(Qb, Kb, Vt, Yb);
  gemm_bt128_kernel<<<(Mrows/128)*(Csz/256), 512, 0, stream>>>(
      Yb, wpT, out, nullptr, nullptr, nullptr, Mrows, Csz, Csz, 0);
}

// Round 6
// 246.531 us; speedup vs baseline: 1.0894x; 1.0894x over previous
//
#include <hip/hip_runtime.h>
#include <hip/hip_bf16.h>
#include <stdint.h>

// Problem constants
#define Bsz 4
#define Tsz 2048
#define Csz 1024
#define Hn  16
#define Dh  64
#define BH  (Bsz*Hn)      // 64
#define Mrows (Bsz*Tsz)   // 8192
#define N1  (3*Csz)       // 3072

typedef short s16x8 __attribute__((ext_vector_type(8)));
typedef short s16x4 __attribute__((ext_vector_type(4)));
typedef float fx4   __attribute__((ext_vector_type(4)));

static __device__ __forceinline__ short f2bf(float x) {
  __hip_bfloat16 h = __float2bfloat16(x);   // RNE
  return __builtin_bit_cast(short, h);
}

#define GLDS16(g, l) __builtin_amdgcn_global_load_lds( \
    (const __attribute__((address_space(1))) void*)(g), \
    (__attribute__((address_space(3))) void*)(l), 16, 0, 0)

// ---------- fused prep: f32->bf16 cvt + two weight transposes -------------
// R12: 3 kernels -> 1 (saves ~2 launch gaps ~15 µs; dispatch-sum vs bench
// total shows ~45 µs of inter-dispatch overhead across 6 launches).
// Block-specialized: bid<1024 -> x cvt (grid-stride); next 3072 -> wq
// transpose tiles; last 1024 -> wp transpose tiles. Same inner code as the
// three originals; divergence is block-uniform.
__global__ __launch_bounds__(256) void prep_kernel(
    const float* __restrict__ x,  short* __restrict__ xb,
    const float* __restrict__ wq, short* __restrict__ wqT,
    const float* __restrict__ wp, short* __restrict__ wpT)
{
  const int bid = (int)blockIdx.x;
  if (bid < 1024) {
    // ---- cvt: 8192*1024 f32 -> bf16, float4 chunks ----
    const int n4 = Mrows*Csz/4;
    int i = bid * 256 + threadIdx.x;
    const int stride = 1024 * 256;
    for (; i < n4; i += stride) {
      float4 v = ((const float4*)x)[i];
      s16x4 o;
      o.x = f2bf(v.x); o.y = f2bf(v.y); o.z = f2bf(v.z); o.w = f2bf(v.w);
      ((s16x4*)xb)[i] = o;
    }
    return;
  }
  // ---- transpose tile: (K,N) f32 -> (N,K) bf16 ----
  const float* w; short* wt; int K, N, tb;
  if (bid < 1024 + 3072) { w = wq; wt = wqT; K = Csz; N = N1;  tb = bid - 1024; }
  else                   { w = wp; wt = wpT; K = Csz; N = Csz; tb = bid - 4096; }
  const int nbx = N >> 5;
  const int n0 = (tb % nbx) * 32;
  const int k0 = (tb / nbx) * 32;
  __shared__ float tile[32][33];
  int tc = threadIdx.x & 31;
  int tr = threadIdx.x >> 5;      // 0..7
#pragma unroll
  for (int p = 0; p < 4; p++) {
    int r = tr + p*8;
    tile[r][tc] = w[(size_t)(k0 + r) * N + (n0 + tc)];
  }
  __syncthreads();
#pragma unroll
  for (int p = 0; p < 4; p++) {
    int r = tr + p*8;   // output (n) row
    wt[(size_t)(n0 + r) * K + (k0 + tc)] = f2bf(tile[tc][r]);
  }
}

// ---------------- bf16 MFMA GEMM: C = A * Bt^T (R8 anchor, verbatim) ------
// 128x256 tile, BK=64, 512 thr = 8 waves (2x4), 3-deep LDS (144 KB),
// counted vmcnt(6), XCD-contiguous bijective block swizzle, stage split 3+3
// across the two phases. Best whole-package measurement (R8: 254.8 total).
static __device__ __forceinline__ s16x8 lds_frag(const short* p, int off) {
  return *(const s16x8*)(p + off);
}

#define WAITV(n) __asm__ __volatile__("s_waitcnt vmcnt(" #n ")" ::: "memory")

__global__ __launch_bounds__(512) void gemm_bt_kernel(
    const short* __restrict__ A, const short* __restrict__ Bt,
    float* __restrict__ Cf,
    short* __restrict__ Qo, short* __restrict__ Ko, short* __restrict__ Vo,
    int Mdim, int Ndim, int Kdim, int mode)
{
  __shared__ __align__(16) short sA[3][128*64];   // 3 x 16 KB
  __shared__ __align__(16) short sB[3][256*64];   // 3 x 32 KB
  const int tid  = threadIdx.x;
  const int lane = tid & 63;
  const int lr   = lane & 15;
  const int lq   = lane >> 4;
  const int wv   = tid >> 6;               // 0..7
  const int nb   = Ndim >> 8;              // 256-wide n tiles
  const int nwg  = (int)gridDim.x;
  const int orig = (int)blockIdx.x;
  const int wgid = (orig & 7) * (nwg >> 3) + (orig >> 3);
  const int bm   = wgid / nb;
  const int bn   = wgid % nb;
  const int m_off = (wv & 1) << 6;         // 0 / 64
  const int n_off = (wv >> 1) << 6;        // 0 / 64 / 128 / 192

  const short* Ab = A  + (size_t)bm * 128 * Kdim;
  const short* Bb = Bt + (size_t)bn * 256 * Kdim;

  const short* gA[2];
  const short* gB[4];
#pragma unroll
  for (int j = 0; j < 2; j++) {
    int c = tid + 512*j, r = c >> 3, o = ((c & 7) ^ (r & 7)) * 8;
    gA[j] = Ab + (size_t)r * Kdim + o;
  }
#pragma unroll
  for (int j = 0; j < 4; j++) {
    int c = tid + 512*j, r = c >> 3, o = ((c & 7) ^ (r & 7)) * 8;
    gB[j] = Bb + (size_t)r * Kdim + o;
  }

  int offA[4][2], offB[4][2];
#pragma unroll
  for (int ft = 0; ft < 4; ft++)
#pragma unroll
    for (int kk = 0; kk < 2; kk++) {
      int ra = m_off + ft*16 + lr;
      offA[ft][kk] = ra*64 + ((((kk<<2) | lq) ^ (ra & 7)) << 3);
      int rb = n_off + ft*16 + lr;
      offB[ft][kk] = rb*64 + ((((kk<<2) | lq) ^ (rb & 7)) << 3);
    }

  fx4 acc[4][4];
#pragma unroll
  for (int i = 0; i < 4; i++)
#pragma unroll
    for (int j = 0; j < 4; j++) acc[i][j] = (fx4){0.f, 0.f, 0.f, 0.f};

  auto STAGE_P1 = [&](int k0, short* dA, short* dB) {   // 3 loads
    GLDS16(gA[0] + k0, dA + tid*8);
    GLDS16(gA[1] + k0, dA + (tid+512)*8);
    GLDS16(gB[0] + k0, dB + tid*8);
  };
  auto STAGE_P2 = [&](int k0, short* dB) {              // 3 loads
    GLDS16(gB[1] + k0, dB + (tid+512)*8);
    GLDS16(gB[2] + k0, dB + (tid+1024)*8);
    GLDS16(gB[3] + k0, dB + (tid+1536)*8);
  };

  const int NIT = Kdim >> 6;   // K-tiles of 64 (16 for K=1024)

  STAGE_P1(0,  sA[0], sB[0]); STAGE_P2(0,  sB[0]);
  STAGE_P1(64, sA[1], sB[1]); STAGE_P2(64, sB[1]);
  WAITV(6);
  __builtin_amdgcn_s_barrier();

  const short *cA = sA[0], *cB = sB[0];
  const short *nA = sA[1], *nB = sB[1];
  short *eA = sA[2], *eB = sB[2];

  for (int t = 0; t < NIT; ++t) {
    if (t + 2 < NIT) STAGE_P1((t+2)*64, eA, eB);

    // ---- phase 1: n-frags 0,1 ----
    s16x8 af[4][2], bf[2][2];
#pragma unroll
    for (int mt = 0; mt < 4; mt++)
#pragma unroll
      for (int kk = 0; kk < 2; kk++)
        af[mt][kk] = lds_frag(cA, offA[mt][kk]);
#pragma unroll
    for (int nt = 0; nt < 2; nt++)
#pragma unroll
      for (int kk = 0; kk < 2; kk++)
        bf[nt][kk] = lds_frag(cB, offB[nt][kk]);
    __builtin_amdgcn_s_setprio(1);
#pragma unroll
    for (int kk = 0; kk < 2; kk++)
#pragma unroll
      for (int mt = 0; mt < 4; mt++) {
        acc[mt][0] = __builtin_amdgcn_mfma_f32_16x16x32_bf16(af[mt][kk], bf[0][kk], acc[mt][0], 0, 0, 0);
        acc[mt][1] = __builtin_amdgcn_mfma_f32_16x16x32_bf16(af[mt][kk], bf[1][kk], acc[mt][1], 0, 0, 0);
      }
    __builtin_amdgcn_s_setprio(0);
    __builtin_amdgcn_sched_barrier(0);
    __builtin_amdgcn_s_barrier();

    // ---- phase 2: n-frags 2,3 ----
    if (t + 2 < NIT) STAGE_P2((t+2)*64, eB);
#pragma unroll
    for (int nt = 0; nt < 2; nt++)
#pragma unroll
      for (int kk = 0; kk < 2; kk++)
        bf[nt][kk] = lds_frag(cB, offB[nt+2][kk]);
    __builtin_amdgcn_s_setprio(1);
#pragma unroll
    for (int kk = 0; kk < 2; kk++)
#pragma unroll
      for (int mt = 0; mt < 4; mt++) {
        acc[mt][2] = __builtin_amdgcn_mfma_f32_16x16x32_bf16(af[mt][kk], bf[0][kk], acc[mt][2], 0, 0, 0);
        acc[mt][3] = __builtin_amdgcn_mfma_f32_16x16x32_bf16(af[mt][kk], bf[1][kk], acc[mt][3], 0, 0, 0);
      }
    __builtin_amdgcn_s_setprio(0);
    __builtin_amdgcn_sched_barrier(0);
    if (t + 2 < NIT)      { WAITV(6); }
    else if (t + 1 < NIT) { WAITV(0); }
    __builtin_amdgcn_s_barrier();

    const short *tAp = cA, *tBp = cB;
    cA = nA; cB = nB;
    nA = eA; nB = eB;
    eA = (short*)tAp; eB = (short*)tBp;
  }

  const int gm0 = bm*128 + m_off;
  const int gn0 = bn*256 + n_off;
  if (mode == 0) {
#pragma unroll
    for (int mt = 0; mt < 4; mt++)
#pragma unroll
      for (int nt = 0; nt < 4; nt++) {
        int col = gn0 + nt*16 + lr;
#pragma unroll
        for (int r = 0; r < 4; r++) {
          int row = gm0 + mt*16 + lq*4 + r;
          Cf[(size_t)row * Ndim + col] = acc[mt][nt][r];
        }
      }
  } else {
#pragma unroll
    for (int mt = 0; mt < 4; mt++)
#pragma unroll
      for (int nt = 0; nt < 4; nt++) {
        int n   = gn0 + nt*16 + lr;
        int sec = n >> 10;        // 0=q 1=k 2=v (wave-uniform per nt)
        int cc  = n & 1023;
        int hh  = cc >> 6;
        int dd  = cc & 63;
        if (sec == 2) {
          int tt0 = gm0 + mt*16 + lq*4;
          int bb  = tt0 >> 11;
          int bh  = bb * Hn + hh;
          s16x4 pk;
          pk.x = f2bf(acc[mt][nt][0]); pk.y = f2bf(acc[mt][nt][1]);
          pk.z = f2bf(acc[mt][nt][2]); pk.w = f2bf(acc[mt][nt][3]);
          *(s16x4*)(Vo + ((size_t)bh * Dh + dd) * Tsz + (tt0 & 2047)) = pk;
        } else {
#pragma unroll
          for (int r = 0; r < 4; r++) {
            int m  = gm0 + mt*16 + lq*4 + r;
            int bb = m >> 11;
            int tt = m & 2047;
            int bh = bb * Hn + hh;
            short v = f2bf(acc[mt][nt][r]);
            if (sec == 0) Qo[((size_t)bh * Tsz + tt) * Dh + dd] = v;
            else          Ko[((size_t)bh * Tsz + tt) * Dh + dd] = v;
          }
        }
      }
  }
}

// ---------------- flash-style causal attention (R8 anchor + T5) -----------
// 4 waves / 256 thr, 128 q-rows per block, grid (64,16), heavy-first.
// R12 delta vs R8: s_setprio(1) around both MFMA clusters (m191: attn's
// independent-block regime is where setprio pays; blocks are not lockstep).
#define PPITCH 72   // 64 keys + 8 pad; 2-way banks (free)

static __device__ __forceinline__ void attn_stage(
    const short* __restrict__ Kp, const short* __restrict__ Vp, int kbase,
    short* __restrict__ sK, short* __restrict__ sV,
    int c0, int r0, int g0, int c1, int r1, int g1)
{
  GLDS16(Kp + (size_t)(kbase + r0)*Dh + g0, sK + c0*8);
  GLDS16(Kp + (size_t)(kbase + r1)*Dh + g1, sK + c1*8);
  GLDS16(Vp + (size_t)r0*Tsz + kbase + g0, sV + c0*8);
  GLDS16(Vp + (size_t)r1*Tsz + kbase + g1, sV + c1*8);
}

static __device__ __forceinline__ void attn_compute(
    const short* __restrict__ sK, const short* __restrict__ sV,
    int kbase, int q0, int lr, int lq, int sw,
    short* __restrict__ pb, const s16x8 bq[2][2], fx4 o[2][4], float li[2])
{
  const float sc = 0.125f * 1.44269504f;   // 1/sqrt(64) * log2(e)
  const bool masked = (kbase + 63 > q0);   // wave-uniform

  // S^T = K·Q^T for both q-frags, sharing the K A-frag reads
  fx4 s[2][4];
#pragma unroll
  for (int j = 0; j < 2; j++)
#pragma unroll
    for (int mt = 0; mt < 4; mt++) s[j][mt] = (fx4){0.f,0.f,0.f,0.f};
  __builtin_amdgcn_s_setprio(1);
#pragma unroll
  for (int mt = 0; mt < 4; mt++)
#pragma unroll
    for (int kk = 0; kk < 2; kk++) {
      const s16x8 akf = *(const s16x8*)(sK + (mt*16 + lr)*64 + ((kk*4 + lq) ^ sw)*8);
      s[0][mt] = __builtin_amdgcn_mfma_f32_16x16x32_bf16(akf, bq[0][kk], s[0][mt], 0, 0, 0);
      s[1][mt] = __builtin_amdgcn_mfma_f32_16x16x32_bf16(akf, bq[1][kk], s[1][mt], 0, 0, 0);
    }
  __builtin_amdgcn_s_setprio(0);

  // softmax (no running max) + P^T staging, per q-frag
#pragma unroll
  for (int j = 0; j < 2; j++) {
    const int qg = q0 + 16*j + lr;
    float p[16];
#pragma unroll
    for (int mt = 0; mt < 4; mt++)
#pragma unroll
      for (int r = 0; r < 4; r++) {
        float v = s[j][mt][r];
        if (masked) {
          int jg = kbase + mt*16 + lq*4 + r;
          v = (jg <= qg) ? v : -1e30f;
        }
        p[mt*4 + r] = __builtin_amdgcn_exp2f(v * sc);
      }
    float s8[8];
#pragma unroll
    for (int i = 0; i < 8; i++) s8[i] = p[i] + p[i+8];
    float s4[4];
#pragma unroll
    for (int i = 0; i < 4; i++) s4[i] = s8[i] + s8[i+4];
    li[j] += (s4[0] + s4[2]) + (s4[1] + s4[3]);
#pragma unroll
    for (int mt = 0; mt < 4; mt++) {
      s16x4 pk;
      pk.x = f2bf(p[mt*4+0]); pk.y = f2bf(p[mt*4+1]);
      pk.z = f2bf(p[mt*4+2]); pk.w = f2bf(p[mt*4+3]);
      *(s16x4*)(pb + (16*j + lr)*PPITCH + mt*16 + lq*4) = pk;
    }
  }
  __asm__ __volatile__("" ::: "memory");  // pin pbuf write->read (DS in-order/wave)
  s16x8 pf[2][2];
#pragma unroll
  for (int j = 0; j < 2; j++)
#pragma unroll
    for (int kk = 0; kk < 2; kk++)
      pf[j][kk] = *(const s16x8*)(pb + (16*j + lr)*PPITCH + kk*32 + lq*8);
  __asm__ __volatile__("" ::: "memory");  // pin reads before next tile's writes

  // O^T += V^T·P^T, sharing the V A-frag reads across q-frags
  __builtin_amdgcn_s_setprio(1);
#pragma unroll
  for (int dt = 0; dt < 4; dt++)
#pragma unroll
    for (int kk = 0; kk < 2; kk++) {
      const s16x8 avf = *(const s16x8*)(sV + (dt*16 + lr)*64 + ((kk*4 + lq) ^ sw)*8);
      o[0][dt] = __builtin_amdgcn_mfma_f32_16x16x32_bf16(avf, pf[0][kk], o[0][dt], 0, 0, 0);
      o[1][dt] = __builtin_amdgcn_mfma_f32_16x16x32_bf16(avf, pf[1][kk], o[1][dt], 0, 0, 0);
    }
  __builtin_amdgcn_s_setprio(0);
}

__global__ __launch_bounds__(256) void attn_kernel(
    const short* __restrict__ Qb, const short* __restrict__ Kb,
    const short* __restrict__ Vt, short* __restrict__ Y)
{
  __shared__ __align__(16) short sK[2][64*64];     // 2 x 8 KB
  __shared__ __align__(16) short sV[2][64*64];     // 2 x 8 KB
  __shared__ __align__(16) short pbuf[4][32*PPITCH];
  const int tid  = threadIdx.x;
  const int lane = tid & 63;
  const int wv   = tid >> 6;
  const int lr   = lane & 15;
  const int lq   = lane >> 4;
  const int sw   = lr & 7;
  const int bh   = blockIdx.x;
  const int qb   = 15 - (int)blockIdx.y;   // heavy blocks first
  const int b    = bh >> 4;
  const int h    = bh & 15;
  const int q0   = qb*128 + wv*32;         // wave covers q0..q0+31

  const short* Qp = Qb + (size_t)bh * Tsz * Dh;
  const short* Kp = Kb + (size_t)bh * Tsz * Dh;
  const short* Vp = Vt + (size_t)bh * Dh * Tsz;
  short* pb = pbuf[wv];

  const int c0 = tid,       r0 = c0 >> 3, g0 = (((c0 & 7) ^ (r0 & 7)) * 8);
  const int c1 = tid + 256, r1 = c1 >> 3, g1 = (((c1 & 7) ^ (r1 & 7)) * 8);

  // Q B-frags for both q-subtiles: B[k=d(lq*8+j)][n=q(lr)]
  s16x8 bq[2][2];
#pragma unroll
  for (int j = 0; j < 2; j++)
#pragma unroll
    for (int kk = 0; kk < 2; kk++)
      bq[j][kk] = *(const s16x8*)(Qp + (size_t)(q0 + 16*j + lr)*Dh + kk*32 + lq*8);

  fx4 o[2][4];
#pragma unroll
  for (int j = 0; j < 2; j++)
#pragma unroll
    for (int i = 0; i < 4; i++) o[j][i] = (fx4){0.f, 0.f, 0.f, 0.f};
  float li[2] = {0.f, 0.f};

  const int ntiles = 2*qb + 2;             // even; keys 0 .. qb*128+127
  attn_stage(Kp, Vp, 0, sK[0], sV[0], c0, r0, g0, c1, r1, g1);
  for (int kt = 0; kt < ntiles; kt += 2) {
    __syncthreads();
    if (kt + 1 < ntiles) attn_stage(Kp, Vp, (kt+1)*64, sK[1], sV[1], c0, r0, g0, c1, r1, g1);
    if (kt*64 <= q0 + 31)
      attn_compute(sK[0], sV[0], kt*64, q0, lr, lq, sw, pb, bq, o, li);
    __syncthreads();
    if (kt + 2 < ntiles) attn_stage(Kp, Vp, (kt+2)*64, sK[0], sV[0], c0, r0, g0, c1, r1, g1);
    if ((kt+1)*64 <= q0 + 31)
      attn_compute(sK[1], sV[1], (kt+1)*64, q0, lr, lq, sw, pb, bq, o, li);
  }

  // combine the 4 lq-replica partial sums; write O^T (lane q fixed per frag)
#pragma unroll
  for (int j = 0; j < 2; j++) {
    float l = li[j];
    l += __shfl_xor(l, 16);
    l += __shfl_xor(l, 32);
    float inv = 1.0f / l;
#pragma unroll
    for (int dt = 0; dt < 4; dt++) {
      s16x4 yk;
      yk.x = f2bf(o[j][dt][0]*inv); yk.y = f2bf(o[j][dt][1]*inv);
      yk.z = f2bf(o[j][dt][2]*inv); yk.w = f2bf(o[j][dt][3]*inv);
      *(s16x4*)(Y + ((size_t)b*Tsz + q0 + 16*j + lr)*Csz + h*Dh + dt*16 + lq*4) = yk;
    }
  }
}

// ---------------- launcher (4 dispatches, was 6) ----------------
extern "C" void kernel_launch(void* const* d_in, const int* in_sizes, int n_in,
                              void* d_out, int out_size, void* d_ws, size_t ws_size,
                              hipStream_t stream)
{
  const float* x  = (const float*)d_in[0];
  const float* wq = (const float*)d_in[1];   // (C, 3C)
  const float* wp = (const float*)d_in[2];   // (C, C)
  float* out = (float*)d_out;

  char* ws = (char*)d_ws;
  size_t off = 0;
  short* xb  = (short*)(ws + off); off += (size_t)Mrows*Csz*2;
  short* wqT = (short*)(ws + off); off += (size_t)N1*Csz*2;
  short* wpT = (short*)(ws + off); off += (size_t)Csz*Csz*2;
  short* Qb  = (short*)(ws + off); off += (size_t)BH*Tsz*Dh*2;
  short* Kb  = (short*)(ws + off); off += (size_t)BH*Tsz*Dh*2;
  short* Vt  = (short*)(ws + off); off += (size_t)BH*Dh*Tsz*2;
  short* Yb  = (short*)(ws + off); off += (size_t)Mrows*Csz*2;

  // 1024 cvt blocks + 3072 wq tiles + 1024 wp tiles
  prep_kernel<<<1024 + 3072 + 1024, 256, 0, stream>>>(x, xb, wq, wqT, wp, wpT);
  gemm_bt_kernel<<<(Mrows/128)*(N1/256), 512, 0, stream>>>(
      xb, wqT, nullptr, Qb, Kb, Vt, Mrows, N1, Csz, 1);
  attn_kernel<<<dim3(BH, Tsz/128), 256, 0, stream>>>(Qb, Kb, Vt, Yb);
  gemm_bt_kernel<<<(Mrows/128)*(Csz/256), 512, 0, stream>>>(
      Yb, wpT, out, nullptr, nullptr, nullptr, Mrows, Csz, Csz, 0);
}